// Round 1
// baseline (574.314 us; speedup 1.0000x reference)
//
#include <hip/hip_runtime.h>
#include <hip/hip_bf16.h>

typedef __hip_bfloat16 bf16;
using f32x4 = __attribute__((ext_vector_type(4))) float;
using s16x8 = __attribute__((ext_vector_type(8))) short;

#define S_TOT 2274
#define S_PAD 2304
#define TTXT 226
#define DIMN 1920
#define NH 30
#define HD 64

// ---------------- prep: f32 -> bf16 ----------------
__global__ void k_prep_h(const float* __restrict__ hid, const float* __restrict__ enc,
                         bf16* __restrict__ h_bf) {
  long i = (long)blockIdx.x * blockDim.x + threadIdx.x;
  const long n = (long)S_TOT * DIMN;
  if (i >= n) return;
  int s = (int)(i / DIMN);
  float v = (s < TTXT) ? enc[i] : hid[i - (long)TTXT * DIMN];
  h_bf[i] = __float2bfloat16(v);
}

__global__ void k_prep_wqkv(const float* __restrict__ Wq, const float* __restrict__ Wk,
                            const float* __restrict__ Wv, bf16* __restrict__ w_bf) {
  long i = (long)blockIdx.x * blockDim.x + threadIdx.x;
  const long per = (long)DIMN * DIMN;
  if (i >= 3 * per) return;
  float v = (i < per) ? Wq[i] : (i < 2 * per) ? Wk[i - per] : Wv[i - 2 * per];
  w_bf[i] = __float2bfloat16(v);
}

__global__ void k_prep_wo(const float* __restrict__ Wo, bf16* __restrict__ w_bf) {
  long i = (long)blockIdx.x * blockDim.x + threadIdx.x;
  const long per = (long)DIMN * DIMN;
  if (i >= per) return;
  w_bf[i] = __float2bfloat16(Wo[i]);
}

// ---------------- GEMM: C[M][N] = A[M][K] * B[N][K]^T (B^T layout) ----------------
// MODE 0: plain fp32 write (qkv_raw).  MODE 1: +bias, reorder rows (vid first), fp32 out.
template <int MODE>
__global__ __launch_bounds__(256) void k_gemm_bt(
    const bf16* __restrict__ A, const bf16* __restrict__ B, float* __restrict__ C,
    int M, int N, int K, const float* __restrict__ bias) {
  __shared__ bf16 As[64][32];
  __shared__ bf16 Bs[64][32];
  const int tid = threadIdx.x;
  const int wave = tid >> 6, lane = tid & 63;
  const int mt = blockIdx.y, nt = blockIdx.x;
  const int lrow = tid >> 2, lk = (tid & 3) * 8;
  const int arow = mt * 64 + lrow;
  const long aoff = (long)arow * K + lk;
  const long boff = (long)(nt * 64 + lrow) * K + lk;
  f32x4 acc[4];
#pragma unroll
  for (int j = 0; j < 4; ++j) acc[j] = f32x4{0.f, 0.f, 0.f, 0.f};

  for (int kb = 0; kb < K; kb += 32) {
    float4 av = make_float4(0.f, 0.f, 0.f, 0.f);
    if (arow < M) av = *reinterpret_cast<const float4*>(A + aoff + kb);
    float4 bv = *reinterpret_cast<const float4*>(B + boff + kb);
    __syncthreads();  // previous iteration's frag reads done before overwrite
    *reinterpret_cast<float4*>(&As[lrow][lk]) = av;
    *reinterpret_cast<float4*>(&Bs[lrow][lk]) = bv;
    __syncthreads();
    s16x8 af = *reinterpret_cast<const s16x8*>(&As[wave * 16 + (lane & 15)][(lane >> 4) * 8]);
#pragma unroll
    for (int j = 0; j < 4; ++j) {
      s16x8 bfr = *reinterpret_cast<const s16x8*>(&Bs[j * 16 + (lane & 15)][(lane >> 4) * 8]);
      acc[j] = __builtin_amdgcn_mfma_f32_16x16x32_bf16(af, bfr, acc[j], 0, 0, 0);
    }
  }

#pragma unroll
  for (int j = 0; j < 4; ++j) {
    const int col = nt * 64 + (lane & 15) + 16 * j;
#pragma unroll
    for (int r = 0; r < 4; ++r) {
      const int row = mt * 64 + wave * 16 + (lane >> 4) * 4 + r;
      if (row < M) {
        if (MODE == 0) {
          C[(long)row * N + col] = acc[j][r];
        } else {
          int dst = (row >= TTXT) ? (row - TTXT) : (row + (S_TOT - TTXT));
          C[(long)dst * N + col] = acc[j][r] + bias[col];
        }
      }
    }
  }
}

// ---------------- LN + bias + RoPE + repack (1 wave = 1 (token,head)) ----------------
__global__ __launch_bounds__(64) void k_ln_rope_pack(
    const float* __restrict__ qkv, const float* __restrict__ bq, const float* __restrict__ bk,
    const float* __restrict__ bv, const float* __restrict__ lqw, const float* __restrict__ lqb,
    const float* __restrict__ lkw, const float* __restrict__ lkb, const float* __restrict__ cosT,
    const float* __restrict__ sinT, bf16* __restrict__ qb, bf16* __restrict__ kbf,
    bf16* __restrict__ vt) {
  const int bid = blockIdx.x;
  const int s = bid / NH, h = bid % NH;
  const int d = threadIdx.x;
  const long qk_idx = ((long)h * S_PAD + s) * HD + d;
  const long vt_idx = ((long)h * HD + d) * S_PAD + s;
  if (s >= S_TOT) {  // zero the pad rows every call (ws is not re-poisoned consistently)
    qb[qk_idx] = __float2bfloat16(0.f);
    kbf[qk_idx] = __float2bfloat16(0.f);
    vt[vt_idx] = __float2bfloat16(0.f);
    return;
  }
  const long base = (long)s * (3 * DIMN) + h * HD + d;
  float qv = qkv[base] + bq[h * HD + d];
  float kv = qkv[base + DIMN] + bk[h * HD + d];
  float vv = qkv[base + 2 * DIMN] + bv[h * HD + d];

  auto ln64 = [&](float x, float w, float b2) {
    float sum = x, sq = x * x;
#pragma unroll
    for (int m = 32; m >= 1; m >>= 1) {
      sum += __shfl_xor(sum, m);
      sq += __shfl_xor(sq, m);
    }
    float mu = sum * (1.f / 64.f);
    float var = sq * (1.f / 64.f) - mu * mu;  // biased var, matches jnp.var
    return (x - mu) * rsqrtf(var + 1e-5f) * w + b2;
  };
  float qn = ln64(qv, lqw[d], lqb[d]);
  float kn = ln64(kv, lkw[d], lkb[d]);
  if (s >= TTXT) {  // block-uniform branch
    const long ri = (long)(s - TTXT) * HD + d;
    float c = cosT[ri], sn = sinT[ri];
    float qp = __shfl_xor(qn, 1);
    float kp = __shfl_xor(kn, 1);
    float sgn = (d & 1) ? 1.f : -1.f;  // even d: -x[d+1]*sin ; odd d: +x[d-1]*sin
    qn = qn * c + sgn * qp * sn;
    kn = kn * c + sgn * kp * sn;
  }
  qb[qk_idx] = __float2bfloat16(qn);
  kbf[qk_idx] = __float2bfloat16(kn);
  vt[vt_idx] = __float2bfloat16(vv);
}

// ---------------- flash attention: 1 block = (head, 64-row q-tile), 4 waves ----------------
__global__ __launch_bounds__(256) void k_flash(const bf16* __restrict__ qb,
                                               const bf16* __restrict__ kbf,
                                               const bf16* __restrict__ vt,
                                               bf16* __restrict__ ao) {
  const int h = blockIdx.x, qt = blockIdx.y;
  const int tid = threadIdx.x, wave = tid >> 6, lane = tid & 63;
  const bf16* Qh = qb + (long)h * S_PAD * HD;
  const bf16* Kh = kbf + (long)h * S_PAD * HD;
  const bf16* Vh = vt + (long)h * HD * S_PAD;
  __shared__ bf16 Pl[4][16][64];  // per-wave private P tile
  const int q0 = qt * 64 + wave * 16;
  const int qr = q0 + (lane & 15);
  s16x8 qf[2];
  qf[0] = *reinterpret_cast<const s16x8*>(Qh + (long)qr * HD + (lane >> 4) * 8);
  qf[1] = *reinterpret_cast<const s16x8*>(Qh + (long)qr * HD + 32 + (lane >> 4) * 8);
  f32x4 accO[4];
  float m_run[4], l_run[4];
#pragma unroll
  for (int r = 0; r < 4; ++r) {
    accO[r] = f32x4{0.f, 0.f, 0.f, 0.f};
    m_run[r] = -1e30f;
    l_run[r] = 0.f;
  }

  for (int kt = 0; kt < S_PAD / 64; ++kt) {
    const int kb0 = kt * 64;
    f32x4 sc[4];
#pragma unroll
    for (int j = 0; j < 4; ++j) sc[j] = f32x4{0.f, 0.f, 0.f, 0.f};
#pragma unroll
    for (int j = 0; j < 4; ++j) {
      const long krow = kb0 + j * 16 + (lane & 15);
      s16x8 kf0 = *reinterpret_cast<const s16x8*>(Kh + krow * HD + (lane >> 4) * 8);
      s16x8 kf1 = *reinterpret_cast<const s16x8*>(Kh + krow * HD + 32 + (lane >> 4) * 8);
      sc[j] = __builtin_amdgcn_mfma_f32_16x16x32_bf16(qf[0], kf0, sc[j], 0, 0, 0);
      sc[j] = __builtin_amdgcn_mfma_f32_16x16x32_bf16(qf[1], kf1, sc[j], 0, 0, 0);
    }
    // scale + key mask
#pragma unroll
    for (int j = 0; j < 4; ++j) {
      const int key = kb0 + (lane & 15) + 16 * j;
      const bool valid = key < S_TOT;
#pragma unroll
      for (int r = 0; r < 4; ++r) sc[j][r] = valid ? sc[j][r] * 0.125f : -1e30f;
    }
    // online softmax (row r lives in reg r across the 16-lane group)
    float mt_[4], corr[4];
#pragma unroll
    for (int r = 0; r < 4; ++r) {
      float v = fmaxf(fmaxf(sc[0][r], sc[1][r]), fmaxf(sc[2][r], sc[3][r]));
#pragma unroll
      for (int m = 1; m < 16; m <<= 1) v = fmaxf(v, __shfl_xor(v, m));
      mt_[r] = v;
    }
#pragma unroll
    for (int r = 0; r < 4; ++r) {
      float mn = fmaxf(m_run[r], mt_[r]);
      corr[r] = __expf(m_run[r] - mn);
      m_run[r] = mn;
    }
    float rs[4] = {0.f, 0.f, 0.f, 0.f};
#pragma unroll
    for (int j = 0; j < 4; ++j)
#pragma unroll
      for (int r = 0; r < 4; ++r) {
        float p = __expf(sc[j][r] - m_run[r]);
        sc[j][r] = p;
        rs[r] += p;
      }
#pragma unroll
    for (int r = 0; r < 4; ++r) {
      float v = rs[r];
#pragma unroll
      for (int m = 1; m < 16; m <<= 1) v += __shfl_xor(v, m);
      l_run[r] = l_run[r] * corr[r] + v;
#pragma unroll
      for (int j = 0; j < 4; ++j) accO[j][r] *= corr[r];
    }
    // P (score layout) -> LDS -> A-fragment layout
#pragma unroll
    for (int j = 0; j < 4; ++j)
#pragma unroll
      for (int r = 0; r < 4; ++r)
        Pl[wave][(lane >> 4) * 4 + r][(lane & 15) + 16 * j] = __float2bfloat16(sc[j][r]);
    __syncthreads();
#pragma unroll
    for (int ks = 0; ks < 2; ++ks) {
      s16x8 pf = *reinterpret_cast<const s16x8*>(&Pl[wave][lane & 15][ks * 32 + (lane >> 4) * 8]);
#pragma unroll
      for (int j2 = 0; j2 < 4; ++j2) {
        s16x8 vf = *reinterpret_cast<const s16x8*>(
            Vh + (long)((lane & 15) + 16 * j2) * S_PAD + kb0 + ks * 32 + (lane >> 4) * 8);
        accO[j2] = __builtin_amdgcn_mfma_f32_16x16x32_bf16(pf, vf, accO[j2], 0, 0, 0);
      }
    }
    __syncthreads();
  }
#pragma unroll
  for (int j2 = 0; j2 < 4; ++j2) {
    const int col = (lane & 15) + 16 * j2;
#pragma unroll
    for (int r = 0; r < 4; ++r) {
      const int srow = q0 + (lane >> 4) * 4 + r;
      if (srow < S_TOT)
        ao[(long)srow * DIMN + h * HD + col] = __float2bfloat16(accO[j2][r] / l_run[r]);
    }
  }
}

extern "C" void kernel_launch(void* const* d_in, const int* in_sizes, int n_in, void* d_out,
                              int out_size, void* d_ws, size_t ws_size, hipStream_t stream) {
  const float* hid = (const float*)d_in[0];
  const float* enc = (const float*)d_in[1];
  const float* rc = (const float*)d_in[2];
  const float* rs = (const float*)d_in[3];
  const float* Wq = (const float*)d_in[4];
  const float* bq = (const float*)d_in[5];
  const float* Wk = (const float*)d_in[6];
  const float* bk = (const float*)d_in[7];
  const float* Wv = (const float*)d_in[8];
  const float* bv = (const float*)d_in[9];
  const float* lqw = (const float*)d_in[10];
  const float* lqb = (const float*)d_in[11];
  const float* lkw = (const float*)d_in[12];
  const float* lkb = (const float*)d_in[13];
  const float* Wo = (const float*)d_in[14];
  const float* bo = (const float*)d_in[15];
  float* out = (float*)d_out;

  char* ws = (char*)d_ws;
  size_t off = 0;
  float* qkv_raw = (float*)(ws + off);
  off += (size_t)S_PAD * 5760 * 4;  // 53.1 MB
  bf16* h_bf = (bf16*)(ws + off);
  off += (size_t)S_PAD * DIMN * 2;  // 8.8 MB
  bf16* wqkv = (bf16*)(ws + off);
  off += (size_t)3 * DIMN * DIMN * 2;  // 22.1 MB
  bf16* wo = (bf16*)(ws + off);
  off += (size_t)DIMN * DIMN * 2;  // 7.4 MB
  bf16* q_bf = (bf16*)(ws + off);
  off += (size_t)NH * S_PAD * HD * 2;  // 8.8 MB
  bf16* k_bf = (bf16*)(ws + off);
  off += (size_t)NH * S_PAD * HD * 2;  // 8.8 MB
  bf16* vt_bf = (bf16*)(ws + off);
  off += (size_t)NH * HD * S_PAD * 2;  // 8.8 MB
  bf16* at_bf = (bf16*)(ws + off);
  off += (size_t)S_PAD * DIMN * 2;  // 8.8 MB  (total ~121 MB)

  k_prep_h<<<(S_TOT * DIMN + 255) / 256, 256, 0, stream>>>(hid, enc, h_bf);
  k_prep_wqkv<<<(3 * DIMN * DIMN + 255) / 256, 256, 0, stream>>>(Wq, Wk, Wv, wqkv);
  k_prep_wo<<<(DIMN * DIMN + 255) / 256, 256, 0, stream>>>(Wo, wo);
  k_gemm_bt<0><<<dim3(5760 / 64, (S_TOT + 63) / 64), 256, 0, stream>>>(
      h_bf, wqkv, qkv_raw, S_TOT, 5760, DIMN, nullptr);
  k_ln_rope_pack<<<S_PAD * NH, 64, 0, stream>>>(qkv_raw, bq, bk, bv, lqw, lqb, lkw, lkb, rc, rs,
                                                q_bf, k_bf, vt_bf);
  k_flash<<<dim3(NH, S_PAD / 64), 256, 0, stream>>>(q_bf, k_bf, vt_bf, at_bf);
  k_gemm_bt<1><<<dim3(DIMN / 64, (S_TOT + 63) / 64), 256, 0, stream>>>(at_bf, wo, out, S_TOT,
                                                                       DIMN, DIMN, bo);
}

// Round 2
// 374.044 us; speedup vs baseline: 1.5354x; 1.5354x over previous
//
#include <hip/hip_runtime.h>
#include <hip/hip_bf16.h>

typedef __hip_bfloat16 bf16;
using f32x4 = __attribute__((ext_vector_type(4))) float;
using s16x8 = __attribute__((ext_vector_type(8))) short;

#define S_TOT 2274
#define S_PAD 2304
#define TTXT 226
#define DIMN 1920
#define NH 30
#define HD 64
#define NQKV 5760

#define GLOAD_LDS16(g, l)                                                              \
  __builtin_amdgcn_global_load_lds((const __attribute__((address_space(1))) void*)(g), \
                                   (__attribute__((address_space(3))) void*)(l), 16, 0, 0)

// ---------------- prep: f32 -> bf16 ----------------
__global__ void k_prep_h(const float* __restrict__ hid, const float* __restrict__ enc,
                         bf16* __restrict__ h_bf) {
  long i = (long)blockIdx.x * blockDim.x + threadIdx.x;
  if (i >= (long)S_PAD * DIMN) return;
  int s = (int)(i / DIMN);
  float v = (s < TTXT) ? enc[i] : (s < S_TOT ? hid[i - (long)TTXT * DIMN] : 0.f);
  h_bf[i] = __float2bfloat16(v);
}

__global__ void k_prep_wqkv(const float* __restrict__ Wq, const float* __restrict__ Wk,
                            const float* __restrict__ Wv, bf16* __restrict__ w_bf) {
  long i = (long)blockIdx.x * blockDim.x + threadIdx.x;
  const long per = (long)DIMN * DIMN;
  if (i >= 3 * per) return;
  float v = (i < per) ? Wq[i] : (i < 2 * per) ? Wk[i - per] : Wv[i - 2 * per];
  w_bf[i] = __float2bfloat16(v);
}

__global__ void k_prep_wo(const float* __restrict__ Wo, bf16* __restrict__ w_bf) {
  long i = (long)blockIdx.x * blockDim.x + threadIdx.x;
  if (i >= (long)DIMN * DIMN) return;
  w_bf[i] = __float2bfloat16(Wo[i]);
}

// ---------------- GEMM (m97 structure): 128x128 tile, BK=32, dbuf, global_load_lds ----
// C[M=2304][N] = A[2304][K] * B[N][K]^T. MODE 0: plain. MODE 1: +bias, row reorder, guard.
template <int MODE>
__global__ __launch_bounds__(256) void k_gemm128(const bf16* __restrict__ A,
                                                 const bf16* __restrict__ B,
                                                 float* __restrict__ C, int N, int K,
                                                 const float* __restrict__ bias) {
  __shared__ __align__(16) char smem[32768];  // buf b: A @ b*16384, B @ b*16384+8192
  const int tid = threadIdx.x;
  const int w = tid >> 6, lane = tid & 63;
  const int clo = lane & 15, lhi = lane >> 4;
  const int wr = w >> 1, wc = w & 1;
  const int m0 = blockIdx.y * 128, n0 = blockIdx.x * 128;

  // staging: slot u = c*256+tid -> row=u>>2, chunk=u&3; LDS linear [128][32] bf16
  const int srow = tid >> 2, schunk = tid & 3;
  const long agoff0 = (long)(m0 + srow) * K + schunk * 8;
  const long agoff1 = agoff0 + (long)64 * K;
  const long bgoff0 = (long)(n0 + srow) * K + schunk * 8;
  const long bgoff1 = bgoff0 + (long)64 * K;
  const int ldsb = w * 1024;

  f32x4 acc[4][4] = {};

  auto stage = [&](int b, int kb) {
    char* Abuf = &smem[b * 16384];
    char* Bbuf = &smem[b * 16384 + 8192];
    GLOAD_LDS16(A + agoff0 + kb, Abuf + ldsb);
    GLOAD_LDS16(A + agoff1 + kb, Abuf + 4096 + ldsb);
    GLOAD_LDS16(B + bgoff0 + kb, Bbuf + ldsb);
    GLOAD_LDS16(B + bgoff1 + kb, Bbuf + 4096 + ldsb);
  };

  stage(0, 0);
  __syncthreads();
  const int NKS = K / 32;
  int cur = 0;
  for (int ks = 0; ks < NKS; ++ks) {
    if (ks + 1 < NKS) stage(cur ^ 1, (ks + 1) * 32);
    const char* Abuf = &smem[cur * 16384];
    const char* Bbuf = &smem[cur * 16384 + 8192];
    s16x8 af[4], bfr[4];
#pragma unroll
    for (int m = 0; m < 4; ++m)
      af[m] = *reinterpret_cast<const s16x8*>(Abuf + (wr * 64 + m * 16 + clo) * 64 + lhi * 16);
#pragma unroll
    for (int n = 0; n < 4; ++n)
      bfr[n] = *reinterpret_cast<const s16x8*>(Bbuf + (wc * 64 + n * 16 + clo) * 64 + lhi * 16);
#pragma unroll
    for (int m = 0; m < 4; ++m)
#pragma unroll
      for (int n = 0; n < 4; ++n)
        acc[m][n] = __builtin_amdgcn_mfma_f32_16x16x32_bf16(af[m], bfr[n], acc[m][n], 0, 0, 0);
    __syncthreads();
    cur ^= 1;
  }
#pragma unroll
  for (int n = 0; n < 4; ++n) {
    const int col = n0 + wc * 64 + n * 16 + clo;
    const float bv = (MODE == 1) ? bias[col] : 0.f;
#pragma unroll
    for (int m = 0; m < 4; ++m) {
#pragma unroll
      for (int r = 0; r < 4; ++r) {
        const int row = m0 + wr * 64 + m * 16 + lhi * 4 + r;
        if (MODE == 0) {
          C[(long)row * N + col] = acc[m][n][r];
        } else if (row < S_TOT) {
          const int dst = (row >= TTXT) ? (row - TTXT) : (row + (S_TOT - TTXT));
          C[(long)dst * N + col] = acc[m][n][r] + bv;
        }
      }
    }
  }
}

// ---------------- LN + bias + RoPE + repack (1 wave = 1 (token,head), 4 waves/block) ----
__global__ __launch_bounds__(256) void k_ln_rope_pack(
    const float* __restrict__ qkv, const float* __restrict__ bq, const float* __restrict__ bk,
    const float* __restrict__ bv, const float* __restrict__ lqw, const float* __restrict__ lqb,
    const float* __restrict__ lkw, const float* __restrict__ lkb, const float* __restrict__ cosT,
    const float* __restrict__ sinT, bf16* __restrict__ qb, bf16* __restrict__ kbf,
    bf16* __restrict__ vt) {
  const int sh = blockIdx.x * 4 + (threadIdx.x >> 6);
  const int s = sh / NH, h = sh % NH;
  const int d = threadIdx.x & 63;
  const long qk_idx = ((long)h * S_PAD + s) * HD + d;
  const long vt_idx = ((long)h * HD + d) * S_PAD + s;
  if (s >= S_TOT) {  // zero pad rows
    qb[qk_idx] = __float2bfloat16(0.f);
    kbf[qk_idx] = __float2bfloat16(0.f);
    vt[vt_idx] = __float2bfloat16(0.f);
    return;
  }
  const long base = (long)s * NQKV + h * HD + d;
  float qv = qkv[base] + bq[h * HD + d];
  float kv = qkv[base + DIMN] + bk[h * HD + d];
  float vv = qkv[base + 2 * DIMN] + bv[h * HD + d];

  auto ln64 = [&](float x, float w, float b2) {
    float sum = x, sq = x * x;
#pragma unroll
    for (int m = 32; m >= 1; m >>= 1) {
      sum += __shfl_xor(sum, m);
      sq += __shfl_xor(sq, m);
    }
    float mu = sum * (1.f / 64.f);
    float var = sq * (1.f / 64.f) - mu * mu;
    return (x - mu) * rsqrtf(var + 1e-5f) * w + b2;
  };
  float qn = ln64(qv, lqw[d], lqb[d]);
  float kn = ln64(kv, lkw[d], lkb[d]);
  if (s >= TTXT) {  // wave-uniform branch
    const long ri = (long)(s - TTXT) * HD + d;
    float c = cosT[ri], sn = sinT[ri];
    float qp = __shfl_xor(qn, 1);
    float kp = __shfl_xor(kn, 1);
    float sgn = (d & 1) ? 1.f : -1.f;
    qn = qn * c + sgn * qp * sn;
    kn = kn * c + sgn * kp * sn;
  }
  qb[qk_idx] = __float2bfloat16(qn * 0.125f);  // fold 1/sqrt(64) into Q
  kbf[qk_idx] = __float2bfloat16(kn);
  vt[vt_idx] = __float2bfloat16(vv);
}

// ---------------- flash attention v2: 128 q-rows/block, LDS-staged K/V, dbuf ----------
__global__ __launch_bounds__(256) void k_flash2(const bf16* __restrict__ qb,
                                                const bf16* __restrict__ kbf,
                                                const bf16* __restrict__ vt,
                                                bf16* __restrict__ ao) {
  __shared__ __align__(16) char smem[49152];  // KV dbuf 2*16KB, P 4*4KB @32768
  const int h = blockIdx.x, qt = blockIdx.y;
  const int tid = threadIdx.x, w = tid >> 6, lane = tid & 63;
  const int clo = lane & 15, lhi = lane >> 4;
  const int xr = clo & 7;
  const bf16* Qh = qb + (long)h * S_PAD * HD;
  const bf16* Kh = kbf + (long)h * S_PAD * HD;
  const bf16* Vh = vt + (long)h * HD * S_PAD;
  const int q0w = qt * 128 + w * 32;

  s16x8 qf[2][2];
#pragma unroll
  for (int rg = 0; rg < 2; ++rg)
#pragma unroll
    for (int kc = 0; kc < 2; ++kc)
      qf[rg][kc] =
          *reinterpret_cast<const s16x8*>(Qh + (long)(q0w + rg * 16 + clo) * HD + kc * 32 + lhi * 8);

  f32x4 accO[2][4] = {};
  float m_run[2][4], l_run[2][4];
#pragma unroll
  for (int rg = 0; rg < 2; ++rg)
#pragma unroll
    for (int r = 0; r < 4; ++r) {
      m_run[rg][r] = -1e30f;
      l_run[rg][r] = 0.f;
    }

  // staging slots: u = c*256 + w*64 + lane; row=u>>3, chunk=u&7; swizzled global source
  const int su = w * 64 + lane;
  const int sr = su >> 3, sc8 = su & 7;
  const long kg0 = (long)sr * HD + ((sc8 ^ (sr & 7)) * 8);
  const long kg1 = kg0 + (long)32 * HD;  // row+32: (row&7) unchanged
  const long vg0 = (long)sr * S_PAD + ((sc8 ^ (sr & 7)) * 8);
  const long vg1 = vg0 + (long)32 * S_PAD;
  const int ldsb = w * 1024;

  auto stage = [&](int b, int kb0) {
    char* Kb = &smem[b * 16384];
    char* Vb = &smem[b * 16384 + 8192];
    GLOAD_LDS16(Kh + (long)kb0 * HD + kg0, Kb + ldsb);
    GLOAD_LDS16(Kh + (long)kb0 * HD + kg1, Kb + 4096 + ldsb);
    GLOAD_LDS16(Vh + kb0 + vg0, Vb + ldsb);
    GLOAD_LDS16(Vh + kb0 + vg1, Vb + 4096 + ldsb);
  };

  stage(0, 0);
  __syncthreads();
  int cur = 0;
  const int NT = S_PAD / 64;
  char* Pb = &smem[32768 + w * 4096];
  for (int kt = 0; kt < NT; ++kt) {
    if (kt + 1 < NT) stage(cur ^ 1, (kt + 1) * 64);
    const char* Kb = &smem[cur * 16384];
    const char* Vb = &smem[cur * 16384 + 8192];
    // QK^T from LDS (swizzled, conflict-free)
    f32x4 sc[2][4] = {};
#pragma unroll
    for (int j = 0; j < 4; ++j) {
      const int rk = j * 16 + clo;
      s16x8 kf0 = *reinterpret_cast<const s16x8*>(Kb + rk * 128 + ((lhi ^ xr) * 16));
      s16x8 kf1 = *reinterpret_cast<const s16x8*>(Kb + rk * 128 + (((4 + lhi) ^ xr) * 16));
      sc[0][j] = __builtin_amdgcn_mfma_f32_16x16x32_bf16(qf[0][0], kf0, sc[0][j], 0, 0, 0);
      sc[0][j] = __builtin_amdgcn_mfma_f32_16x16x32_bf16(qf[0][1], kf1, sc[0][j], 0, 0, 0);
      sc[1][j] = __builtin_amdgcn_mfma_f32_16x16x32_bf16(qf[1][0], kf0, sc[1][j], 0, 0, 0);
      sc[1][j] = __builtin_amdgcn_mfma_f32_16x16x32_bf16(qf[1][1], kf1, sc[1][j], 0, 0, 0);
    }
    const int kb0 = kt * 64;
    if (kb0 + 64 > S_TOT) {  // tail-only key mask (block-uniform branch)
#pragma unroll
      for (int j = 0; j < 4; ++j) {
        const bool bad = (kb0 + clo + 16 * j) >= S_TOT;
#pragma unroll
        for (int rg = 0; rg < 2; ++rg)
#pragma unroll
          for (int r = 0; r < 4; ++r)
            if (bad) sc[rg][j][r] = -1e30f;
      }
    }
    // online softmax (rows live across 16-lane groups)
#pragma unroll
    for (int rg = 0; rg < 2; ++rg) {
#pragma unroll
      for (int r = 0; r < 4; ++r) {
        float v = fmaxf(fmaxf(sc[rg][0][r], sc[rg][1][r]), fmaxf(sc[rg][2][r], sc[rg][3][r]));
#pragma unroll
        for (int mm = 1; mm < 16; mm <<= 1) v = fmaxf(v, __shfl_xor(v, mm));
        const float mn = fmaxf(m_run[rg][r], v);
        const float corr = __expf(m_run[rg][r] - mn);
        m_run[rg][r] = mn;
        float rs = 0.f;
#pragma unroll
        for (int j = 0; j < 4; ++j) {
          float p = __expf(sc[rg][j][r] - mn);
          sc[rg][j][r] = p;
          rs += p;
        }
#pragma unroll
        for (int mm = 1; mm < 16; mm <<= 1) rs += __shfl_xor(rs, mm);
        l_run[rg][r] = l_run[rg][r] * corr + rs;
#pragma unroll
        for (int j2 = 0; j2 < 4; ++j2) accO[rg][j2][r] *= corr;
      }
    }
    // P -> per-wave LDS (swizzled)
#pragma unroll
    for (int rg = 0; rg < 2; ++rg)
#pragma unroll
      for (int r = 0; r < 4; ++r) {
        const int prow = rg * 16 + lhi * 4 + r;
        const int ra7 = (lhi * 4 + r) & 7;
        char* rowp = Pb + prow * 128 + (clo & 7) * 2;
#pragma unroll
        for (int j = 0; j < 4; ++j) {
          const int swzc = ((clo >> 3) + 2 * j) ^ ra7;
          *reinterpret_cast<bf16*>(rowp + swzc * 16) = __float2bfloat16(sc[rg][j][r]);
        }
      }
    // PV from LDS
#pragma unroll
    for (int ks = 0; ks < 2; ++ks) {
      s16x8 pf[2];
#pragma unroll
      for (int rg = 0; rg < 2; ++rg)
        pf[rg] = *reinterpret_cast<const s16x8*>(Pb + (rg * 16 + clo) * 128 +
                                                 (((ks * 4 + lhi) ^ xr) * 16));
#pragma unroll
      for (int j2 = 0; j2 < 4; ++j2) {
        s16x8 vf = *reinterpret_cast<const s16x8*>(Vb + (j2 * 16 + clo) * 128 +
                                                   (((ks * 4 + lhi) ^ xr) * 16));
        accO[0][j2] = __builtin_amdgcn_mfma_f32_16x16x32_bf16(pf[0], vf, accO[0][j2], 0, 0, 0);
        accO[1][j2] = __builtin_amdgcn_mfma_f32_16x16x32_bf16(pf[1], vf, accO[1][j2], 0, 0, 0);
      }
    }
    __syncthreads();
    cur ^= 1;
  }
#pragma unroll
  for (int rg = 0; rg < 2; ++rg) {
    float inv[4];
#pragma unroll
    for (int r = 0; r < 4; ++r) inv[r] = 1.f / l_run[rg][r];
#pragma unroll
    for (int j2 = 0; j2 < 4; ++j2) {
      const int col = h * HD + clo + 16 * j2;
#pragma unroll
      for (int r = 0; r < 4; ++r) {
        const int srw = q0w + rg * 16 + lhi * 4 + r;
        if (srw < S_TOT)
          ao[(long)srw * DIMN + col] = __float2bfloat16(accO[rg][j2][r] * inv[r]);
      }
    }
  }
}

extern "C" void kernel_launch(void* const* d_in, const int* in_sizes, int n_in, void* d_out,
                              int out_size, void* d_ws, size_t ws_size, hipStream_t stream) {
  const float* hid = (const float*)d_in[0];
  const float* enc = (const float*)d_in[1];
  const float* rc = (const float*)d_in[2];
  const float* rs = (const float*)d_in[3];
  const float* Wq = (const float*)d_in[4];
  const float* bq = (const float*)d_in[5];
  const float* Wk = (const float*)d_in[6];
  const float* bk = (const float*)d_in[7];
  const float* Wv = (const float*)d_in[8];
  const float* bv = (const float*)d_in[9];
  const float* lqw = (const float*)d_in[10];
  const float* lqb = (const float*)d_in[11];
  const float* lkw = (const float*)d_in[12];
  const float* lkb = (const float*)d_in[13];
  const float* Wo = (const float*)d_in[14];
  const float* bo = (const float*)d_in[15];
  float* out = (float*)d_out;

  char* ws = (char*)d_ws;
  size_t off = 0;
  float* qkv_raw = (float*)(ws + off);
  off += (size_t)S_PAD * NQKV * 4;
  bf16* h_bf = (bf16*)(ws + off);
  off += (size_t)S_PAD * DIMN * 2;
  bf16* wqkv = (bf16*)(ws + off);
  off += (size_t)3 * DIMN * DIMN * 2;
  bf16* wo = (bf16*)(ws + off);
  off += (size_t)DIMN * DIMN * 2;
  bf16* q_bf = (bf16*)(ws + off);
  off += (size_t)NH * S_PAD * HD * 2;
  bf16* k_bf = (bf16*)(ws + off);
  off += (size_t)NH * S_PAD * HD * 2;
  bf16* vt_bf = (bf16*)(ws + off);
  off += (size_t)NH * HD * S_PAD * 2;
  bf16* at_bf = (bf16*)(ws + off);
  off += (size_t)S_PAD * DIMN * 2;

  k_prep_h<<<(S_PAD * DIMN + 255) / 256, 256, 0, stream>>>(hid, enc, h_bf);
  k_prep_wqkv<<<(3 * DIMN * DIMN + 255) / 256, 256, 0, stream>>>(Wq, Wk, Wv, wqkv);
  k_prep_wo<<<(DIMN * DIMN + 255) / 256, 256, 0, stream>>>(Wo, wo);
  k_gemm128<0><<<dim3(NQKV / 128, S_PAD / 128), 256, 0, stream>>>(h_bf, wqkv, qkv_raw, NQKV,
                                                                  DIMN, nullptr);
  k_ln_rope_pack<<<S_PAD * NH / 4, 256, 0, stream>>>(qkv_raw, bq, bk, bv, lqw, lqb, lkw, lkb, rc,
                                                     rs, q_bf, k_bf, vt_bf);
  k_flash2<<<dim3(NH, S_PAD / 128), 256, 0, stream>>>(q_bf, k_bf, vt_bf, at_bf);
  k_gemm128<1><<<dim3(DIMN / 128, S_PAD / 128), 256, 0, stream>>>(at_bf, wo, out, DIMN, DIMN, bo);
}

// Round 3
// 307.288 us; speedup vs baseline: 1.8690x; 1.2172x over previous
//
#include <hip/hip_runtime.h>
#include <hip/hip_bf16.h>

typedef __hip_bfloat16 bf16;
using f32x4 = __attribute__((ext_vector_type(4))) float;
using f32x16 = __attribute__((ext_vector_type(16))) float;
using s16x8 = __attribute__((ext_vector_type(8))) short;

#define S_TOT 2274
#define S_PAD 2304
#define TTXT 226
#define DIMN 1920
#define NH 30
#define HD 64
#define NQKV 5760

#define GLOAD_LDS16(g, l)                                                              \
  __builtin_amdgcn_global_load_lds((const __attribute__((address_space(1))) void*)(g), \
                                   (__attribute__((address_space(3))) void*)(l), 16, 0, 0)

// ---------------- prep: f32 -> bf16 (float4-vectorized) ----------------
__global__ void k_prep_h(const float* __restrict__ hid, const float* __restrict__ enc,
                         bf16* __restrict__ h_bf) {
  long i4 = ((long)blockIdx.x * blockDim.x + threadIdx.x) * 4;
  if (i4 >= (long)S_PAD * DIMN) return;
  int s = (int)(i4 / DIMN);
  float4 v = make_float4(0.f, 0.f, 0.f, 0.f);
  if (s < TTXT)
    v = *reinterpret_cast<const float4*>(enc + i4);
  else if (s < S_TOT)
    v = *reinterpret_cast<const float4*>(hid + i4 - (long)TTXT * DIMN);
  union {
    bf16 b[4];
    short4 s4;
  } o;
  o.b[0] = __float2bfloat16(v.x);
  o.b[1] = __float2bfloat16(v.y);
  o.b[2] = __float2bfloat16(v.z);
  o.b[3] = __float2bfloat16(v.w);
  *reinterpret_cast<short4*>(h_bf + i4) = o.s4;
}

__global__ void k_prep_wqkv(const float* __restrict__ Wq, const float* __restrict__ Wk,
                            const float* __restrict__ Wv, bf16* __restrict__ w_bf) {
  long i4 = ((long)blockIdx.x * blockDim.x + threadIdx.x) * 4;
  const long per = (long)DIMN * DIMN;
  if (i4 >= 3 * per) return;
  const float* src = (i4 < per) ? (Wq + i4) : (i4 < 2 * per) ? (Wk + i4 - per) : (Wv + i4 - 2 * per);
  float4 v = *reinterpret_cast<const float4*>(src);
  union {
    bf16 b[4];
    short4 s4;
  } o;
  o.b[0] = __float2bfloat16(v.x);
  o.b[1] = __float2bfloat16(v.y);
  o.b[2] = __float2bfloat16(v.z);
  o.b[3] = __float2bfloat16(v.w);
  *reinterpret_cast<short4*>(w_bf + i4) = o.s4;
}

__global__ void k_prep_wo(const float* __restrict__ Wo, bf16* __restrict__ w_bf) {
  long i4 = ((long)blockIdx.x * blockDim.x + threadIdx.x) * 4;
  if (i4 >= (long)DIMN * DIMN) return;
  float4 v = *reinterpret_cast<const float4*>(Wo + i4);
  union {
    bf16 b[4];
    short4 s4;
  } o;
  o.b[0] = __float2bfloat16(v.x);
  o.b[1] = __float2bfloat16(v.y);
  o.b[2] = __float2bfloat16(v.z);
  o.b[3] = __float2bfloat16(v.w);
  *reinterpret_cast<short4*>(w_bf + i4) = o.s4;
}

// ---------------- GEMM (m97 structure): 128x128 tile, BK=32, dbuf, global_load_lds ----
template <int MODE>
__global__ __launch_bounds__(256) void k_gemm128(const bf16* __restrict__ A,
                                                 const bf16* __restrict__ B,
                                                 float* __restrict__ C, int N, int K,
                                                 const float* __restrict__ bias) {
  __shared__ __align__(16) char smem[32768];
  const int tid = threadIdx.x;
  const int w = tid >> 6, lane = tid & 63;
  const int clo = lane & 15, lhi = lane >> 4;
  const int wr = w >> 1, wc = w & 1;
  const int m0 = blockIdx.y * 128, n0 = blockIdx.x * 128;

  const int srow = tid >> 2, schunk = tid & 3;
  const long agoff0 = (long)(m0 + srow) * K + schunk * 8;
  const long agoff1 = agoff0 + (long)64 * K;
  const long bgoff0 = (long)(n0 + srow) * K + schunk * 8;
  const long bgoff1 = bgoff0 + (long)64 * K;
  const int ldsb = w * 1024;

  f32x4 acc[4][4] = {};

  auto stage = [&](int b, int kb) {
    char* Abuf = &smem[b * 16384];
    char* Bbuf = &smem[b * 16384 + 8192];
    GLOAD_LDS16(A + agoff0 + kb, Abuf + ldsb);
    GLOAD_LDS16(A + agoff1 + kb, Abuf + 4096 + ldsb);
    GLOAD_LDS16(B + bgoff0 + kb, Bbuf + ldsb);
    GLOAD_LDS16(B + bgoff1 + kb, Bbuf + 4096 + ldsb);
  };

  stage(0, 0);
  __syncthreads();
  const int NKS = K / 32;
  int cur = 0;
  for (int ks = 0; ks < NKS; ++ks) {
    if (ks + 1 < NKS) stage(cur ^ 1, (ks + 1) * 32);
    const char* Abuf = &smem[cur * 16384];
    const char* Bbuf = &smem[cur * 16384 + 8192];
    s16x8 af[4], bfr[4];
#pragma unroll
    for (int m = 0; m < 4; ++m)
      af[m] = *reinterpret_cast<const s16x8*>(Abuf + (wr * 64 + m * 16 + clo) * 64 + lhi * 16);
#pragma unroll
    for (int n = 0; n < 4; ++n)
      bfr[n] = *reinterpret_cast<const s16x8*>(Bbuf + (wc * 64 + n * 16 + clo) * 64 + lhi * 16);
#pragma unroll
    for (int m = 0; m < 4; ++m)
#pragma unroll
      for (int n = 0; n < 4; ++n)
        acc[m][n] = __builtin_amdgcn_mfma_f32_16x16x32_bf16(af[m], bfr[n], acc[m][n], 0, 0, 0);
    __syncthreads();
    cur ^= 1;
  }
#pragma unroll
  for (int n = 0; n < 4; ++n) {
    const int col = n0 + wc * 64 + n * 16 + clo;
    const float bv = (MODE == 1) ? bias[col] : 0.f;
#pragma unroll
    for (int m = 0; m < 4; ++m) {
#pragma unroll
      for (int r = 0; r < 4; ++r) {
        const int row = m0 + wr * 64 + m * 16 + lhi * 4 + r;
        if (MODE == 0) {
          C[(long)row * N + col] = acc[m][n][r];
        } else if (row < S_TOT) {
          const int dst = (row >= TTXT) ? (row - TTXT) : (row + (S_TOT - TTXT));
          C[(long)dst * N + col] = acc[m][n][r] + bv;
        }
      }
    }
  }
}

// ---------------- LN + bias + RoPE + repack ----------------
// Q gets 0.125 * log2(e) folded in (softmax later runs in the exp2 domain).
__global__ __launch_bounds__(256) void k_ln_rope_pack(
    const float* __restrict__ qkv, const float* __restrict__ bq, const float* __restrict__ bk,
    const float* __restrict__ bv, const float* __restrict__ lqw, const float* __restrict__ lqb,
    const float* __restrict__ lkw, const float* __restrict__ lkb, const float* __restrict__ cosT,
    const float* __restrict__ sinT, bf16* __restrict__ qb, bf16* __restrict__ kbf,
    bf16* __restrict__ vt) {
  const int sh = blockIdx.x * 4 + (threadIdx.x >> 6);
  const int s = sh / NH, h = sh % NH;
  const int d = threadIdx.x & 63;
  const long qk_idx = ((long)h * S_PAD + s) * HD + d;
  const long vt_idx = ((long)h * HD + d) * S_PAD + s;
  if (s >= S_TOT) {
    qb[qk_idx] = __float2bfloat16(0.f);
    kbf[qk_idx] = __float2bfloat16(0.f);
    vt[vt_idx] = __float2bfloat16(0.f);
    return;
  }
  const long base = (long)s * NQKV + h * HD + d;
  float qv = qkv[base] + bq[h * HD + d];
  float kv = qkv[base + DIMN] + bk[h * HD + d];
  float vv = qkv[base + 2 * DIMN] + bv[h * HD + d];

  auto ln64 = [&](float x, float w, float b2) {
    float sum = x, sq = x * x;
#pragma unroll
    for (int m = 32; m >= 1; m >>= 1) {
      sum += __shfl_xor(sum, m);
      sq += __shfl_xor(sq, m);
    }
    float mu = sum * (1.f / 64.f);
    float var = sq * (1.f / 64.f) - mu * mu;
    return (x - mu) * rsqrtf(var + 1e-5f) * w + b2;
  };
  float qn = ln64(qv, lqw[d], lqb[d]);
  float kn = ln64(kv, lkw[d], lkb[d]);
  if (s >= TTXT) {
    const long ri = (long)(s - TTXT) * HD + d;
    float c = cosT[ri], sn = sinT[ri];
    float qp = __shfl_xor(qn, 1);
    float kp = __shfl_xor(kn, 1);
    float sgn = (d & 1) ? 1.f : -1.f;
    qn = qn * c + sgn * qp * sn;
    kn = kn * c + sgn * kp * sn;
  }
  qb[qk_idx] = __float2bfloat16(qn * 0.1803368801f);  // 0.125 * log2(e)
  kbf[qk_idx] = __float2bfloat16(kn);
  vt[vt_idx] = __float2bfloat16(vv);
}

// ---------------- flash v3: swapped 32x32 QK^T, lane-local softmax, in-reg P ------
__global__ __launch_bounds__(256) void k_flash3(const bf16* __restrict__ qb,
                                                const bf16* __restrict__ kbf,
                                                const bf16* __restrict__ vt,
                                                bf16* __restrict__ ao) {
  __shared__ __align__(16) char smem[32768];  // dbuf: K 8KB + VT 8KB per buffer
  const int h = blockIdx.x, qt = blockIdx.y;
  const int tid = threadIdx.x, w = tid >> 6, lane = tid & 63;
  const int l31 = lane & 31, hf = lane >> 5;
  const bf16* Qh = qb + (long)h * S_PAD * HD;
  const bf16* Kh = kbf + (long)h * S_PAD * HD;
  const bf16* Vh = vt + (long)h * HD * S_PAD;
  const int q0w = qt * 128 + w * 32;

  // Q fragments (B-operand rows): lane holds Q[q0w + l31][16*t + 8*hf + i]
  s16x8 qf[4];
#pragma unroll
  for (int t = 0; t < 4; ++t)
    qf[t] = *reinterpret_cast<const s16x8*>(Qh + (long)(q0w + l31) * HD + t * 16 + hf * 8);

  f32x16 accO[2] = {};        // O[q=pat(reg,hf)][d = db*32 + l31]
  float m_run = -1e30f;       // per-lane: q-row l31 (lane and lane+32 keep identical stats)
  float l_run = 0.f;

  // staging (linear LDS dest, pre-swizzled global source; chunk ^= row&7)
  const int su = w * 64 + lane;
  const int sr = su >> 3, sc8 = su & 7;
  const long kg0 = (long)sr * HD + ((sc8 ^ (sr & 7)) * 8);
  const long kg1 = kg0 + (long)32 * HD;
  const long vg0 = (long)sr * S_PAD + ((sc8 ^ (sr & 7)) * 8);
  const long vg1 = vg0 + (long)32 * S_PAD;
  const int ldsb = w * 1024;

  auto stage = [&](int b, int kb0) {
    char* Kb = &smem[b * 16384];
    char* Vb = &smem[b * 16384 + 8192];
    GLOAD_LDS16(Kh + (long)kb0 * HD + kg0, Kb + ldsb);
    GLOAD_LDS16(Kh + (long)kb0 * HD + kg1, Kb + 4096 + ldsb);
    GLOAD_LDS16(Vh + kb0 + vg0, Vb + ldsb);
    GLOAD_LDS16(Vh + kb0 + vg1, Vb + 4096 + ldsb);
  };

  auto ldsrd = [&](const char* base, int row, int c) {
    return *reinterpret_cast<const s16x8*>(base + row * 128 + ((c ^ (row & 7)) * 16));
  };
  auto pk2 = [&](float a, float b) -> unsigned {
    __hip_bfloat162 t = __float22bfloat162_rn(make_float2(a, b));
    return *reinterpret_cast<unsigned*>(&t);
  };

  stage(0, 0);
  __syncthreads();
  int cur = 0;
  const int NT = S_PAD / 64;
  for (int kt = 0; kt < NT; ++kt) {
    if (kt + 1 < NT) stage(cur ^ 1, (kt + 1) * 64);
    const char* Kb = &smem[cur * 16384];
    const char* Vb = &smem[cur * 16384 + 8192];

    // QK^T swapped: S^T[key][q], key-blocks kb=0,1; lane owns q-row l31, 16 keys/reg-set
    f32x16 s0 = {}, s1 = {};
#pragma unroll
    for (int t = 0; t < 4; ++t) {  // d-steps of 16
      s16x8 k0 = ldsrd(Kb, l31, 2 * t + hf);
      s16x8 k1 = ldsrd(Kb, 32 + l31, 2 * t + hf);
      s0 = __builtin_amdgcn_mfma_f32_32x32x16_bf16(k0, qf[t], s0, 0, 0, 0);
      s1 = __builtin_amdgcn_mfma_f32_32x32x16_bf16(k1, qf[t], s1, 0, 0, 0);
    }
    const int kb0 = kt * 64;
    if (kb0 + 64 > S_TOT) {  // tail key mask (uniform outer branch)
#pragma unroll
      for (int j = 0; j < 16; ++j) {
        const int key = kb0 + (j & 3) + 8 * (j >> 2) + 4 * hf;
        if (key >= S_TOT) s0[j] = -1e30f;
        if (key + 32 >= S_TOT) s1[j] = -1e30f;
      }
    }
    // lane-local max (32 values) + one partner exchange
    float pmax = fmaxf(s0[0], s1[0]);
#pragma unroll
    for (int j = 1; j < 16; ++j) pmax = fmaxf(pmax, fmaxf(s0[j], s1[j]));
    pmax = fmaxf(pmax, __shfl_xor(pmax, 32));
    // T13 defer-max: rescale only if some row grew > 8 (log2 domain)
    if (!__all(pmax - m_run <= 8.f)) {
      const float mnew = fmaxf(m_run, pmax);
      const float corr = exp2f(m_run - mnew);
      m_run = mnew;
      l_run *= corr;
#pragma unroll
      for (int j = 0; j < 16; ++j) {
        const float cj = __shfl(corr, (lane & 32) | ((j & 3) + 8 * (j >> 2) + 4 * hf));
        accO[0][j] *= cj;
        accO[1][j] *= cj;
      }
    }
    // exp2 + row-sum
    float rsum = 0.f;
#pragma unroll
    for (int j = 0; j < 16; ++j) {
      s0[j] = exp2f(s0[j] - m_run);
      s1[j] = exp2f(s1[j] - m_run);
      rsum += s0[j] + s1[j];
    }
    rsum += __shfl_xor(rsum, 32);
    l_run += rsum;

    // pack P -> bf16 words; G[i] = keys 8i+4hf..+3 per key-block
    unsigned gw0[8], gw1[8];
#pragma unroll
    for (int i = 0; i < 4; ++i) {
      gw0[2 * i] = pk2(s0[4 * i], s0[4 * i + 1]);
      gw0[2 * i + 1] = pk2(s0[4 * i + 2], s0[4 * i + 3]);
      gw1[2 * i] = pk2(s1[4 * i], s1[4 * i + 1]);
      gw1[2 * i + 1] = pk2(s1[4 * i + 2], s1[4 * i + 3]);
    }
    // partner exchange + assemble PV A-frags: pa[kb*2+t] covers keys 32kb+16t+8hf+[0..7]
    s16x8 pa[4];
#pragma unroll
    for (int b = 0; b < 2; ++b) {
      unsigned* gw = b ? gw1 : gw0;
#pragma unroll
      for (int t = 0; t < 2; ++t) {
        const unsigned send0 = hf ? gw[4 * t + 0] : gw[4 * t + 2];
        const unsigned send1 = hf ? gw[4 * t + 1] : gw[4 * t + 3];
        const unsigned r0 = __shfl_xor(send0, 32);
        const unsigned r1 = __shfl_xor(send1, 32);
        union {
          unsigned u[4];
          s16x8 v;
        } asm_;
        asm_.u[0] = hf ? r0 : gw[4 * t + 0];
        asm_.u[1] = hf ? r1 : gw[4 * t + 1];
        asm_.u[2] = hf ? gw[4 * t + 2] : r0;
        asm_.u[3] = hf ? gw[4 * t + 3] : r1;
        pa[b * 2 + t] = asm_.v;
      }
    }
    // PV: O[q][d] += P[q][keys] * VT[d][keys]
#pragma unroll
    for (int t4 = 0; t4 < 4; ++t4) {
      s16x8 v0 = ldsrd(Vb, l31, 2 * t4 + hf);
      s16x8 v1 = ldsrd(Vb, 32 + l31, 2 * t4 + hf);
      accO[0] = __builtin_amdgcn_mfma_f32_32x32x16_bf16(pa[t4], v0, accO[0], 0, 0, 0);
      accO[1] = __builtin_amdgcn_mfma_f32_32x32x16_bf16(pa[t4], v1, accO[1], 0, 0, 0);
    }
    __syncthreads();
    cur ^= 1;
  }
  // epilogue: divide by l (broadcast per C/D row), store
  const float linv = 1.f / l_run;
#pragma unroll
  for (int j = 0; j < 16; ++j) {
    const int pat = (j & 3) + 8 * (j >> 2) + 4 * hf;
    const float lj = __shfl(linv, (lane & 32) | pat);
    const int srow = q0w + pat;
    if (srow < S_TOT) {
      ao[(long)srow * DIMN + h * HD + l31] = __float2bfloat16(accO[0][j] * lj);
      ao[(long)srow * DIMN + h * HD + 32 + l31] = __float2bfloat16(accO[1][j] * lj);
    }
  }
}

extern "C" void kernel_launch(void* const* d_in, const int* in_sizes, int n_in, void* d_out,
                              int out_size, void* d_ws, size_t ws_size, hipStream_t stream) {
  const float* hid = (const float*)d_in[0];
  const float* enc = (const float*)d_in[1];
  const float* rc = (const float*)d_in[2];
  const float* rs = (const float*)d_in[3];
  const float* Wq = (const float*)d_in[4];
  const float* bq = (const float*)d_in[5];
  const float* Wk = (const float*)d_in[6];
  const float* bk = (const float*)d_in[7];
  const float* Wv = (const float*)d_in[8];
  const float* bv = (const float*)d_in[9];
  const float* lqw = (const float*)d_in[10];
  const float* lqb = (const float*)d_in[11];
  const float* lkw = (const float*)d_in[12];
  const float* lkb = (const float*)d_in[13];
  const float* Wo = (const float*)d_in[14];
  const float* bo = (const float*)d_in[15];
  float* out = (float*)d_out;

  char* ws = (char*)d_ws;
  size_t off = 0;
  float* qkv_raw = (float*)(ws + off);
  off += (size_t)S_PAD * NQKV * 4;
  bf16* h_bf = (bf16*)(ws + off);
  off += (size_t)S_PAD * DIMN * 2;
  bf16* wqkv = (bf16*)(ws + off);
  off += (size_t)3 * DIMN * DIMN * 2;
  bf16* wo = (bf16*)(ws + off);
  off += (size_t)DIMN * DIMN * 2;
  bf16* q_bf = (bf16*)(ws + off);
  off += (size_t)NH * S_PAD * HD * 2;
  bf16* k_bf = (bf16*)(ws + off);
  off += (size_t)NH * S_PAD * HD * 2;
  bf16* vt_bf = (bf16*)(ws + off);
  off += (size_t)NH * HD * S_PAD * 2;
  bf16* at_bf = (bf16*)(ws + off);
  off += (size_t)S_PAD * DIMN * 2;

  k_prep_h<<<((S_PAD * DIMN) / 4 + 255) / 256, 256, 0, stream>>>(hid, enc, h_bf);
  k_prep_wqkv<<<((3 * DIMN * DIMN) / 4 + 255) / 256, 256, 0, stream>>>(Wq, Wk, Wv, wqkv);
  k_prep_wo<<<((DIMN * DIMN) / 4 + 255) / 256, 256, 0, stream>>>(Wo, wo);
  k_gemm128<0><<<dim3(NQKV / 128, S_PAD / 128), 256, 0, stream>>>(h_bf, wqkv, qkv_raw, NQKV,
                                                                  DIMN, nullptr);
  k_ln_rope_pack<<<S_PAD * NH / 4, 256, 0, stream>>>(qkv_raw, bq, bk, bv, lqw, lqb, lkw, lkb, rc,
                                                     rs, q_bf, k_bf, vt_bf);
  k_flash3<<<dim3(NH, S_PAD / 128), 256, 0, stream>>>(q_bf, k_bf, vt_bf, at_bf);
  k_gemm128<1><<<dim3(DIMN / 128, S_PAD / 128), 256, 0, stream>>>(at_bf, wo, out, DIMN, DIMN, bo);
}

// Round 4
// 291.644 us; speedup vs baseline: 1.9692x; 1.0536x over previous
//
#include <hip/hip_runtime.h>
#include <hip/hip_bf16.h>

typedef __hip_bfloat16 bf16;
using f32x4 = __attribute__((ext_vector_type(4))) float;
using f32x16 = __attribute__((ext_vector_type(16))) float;
using s16x8 = __attribute__((ext_vector_type(8))) short;

#define S_TOT 2274
#define S_PAD 2304
#define TTXT 226
#define DIMN 1920
#define NH 30
#define HD 64
#define NQKV 5760

#define GLOAD_LDS16(g, l)                                                              \
  __builtin_amdgcn_global_load_lds((const __attribute__((address_space(1))) void*)(g), \
                                   (__attribute__((address_space(3))) void*)(l), 16, 0, 0)

// ---------------- prep: f32 -> bf16 (float4-vectorized) ----------------
__global__ void k_prep_h(const float* __restrict__ hid, const float* __restrict__ enc,
                         bf16* __restrict__ h_bf) {
  long i4 = ((long)blockIdx.x * blockDim.x + threadIdx.x) * 4;
  if (i4 >= (long)S_PAD * DIMN) return;
  int s = (int)(i4 / DIMN);
  float4 v = make_float4(0.f, 0.f, 0.f, 0.f);
  if (s < TTXT)
    v = *reinterpret_cast<const float4*>(enc + i4);
  else if (s < S_TOT)
    v = *reinterpret_cast<const float4*>(hid + i4 - (long)TTXT * DIMN);
  union {
    bf16 b[4];
    short4 s4;
  } o;
  o.b[0] = __float2bfloat16(v.x);
  o.b[1] = __float2bfloat16(v.y);
  o.b[2] = __float2bfloat16(v.z);
  o.b[3] = __float2bfloat16(v.w);
  *reinterpret_cast<short4*>(h_bf + i4) = o.s4;
}

__global__ void k_prep_wqkv(const float* __restrict__ Wq, const float* __restrict__ Wk,
                            const float* __restrict__ Wv, bf16* __restrict__ w_bf) {
  long i4 = ((long)blockIdx.x * blockDim.x + threadIdx.x) * 4;
  const long per = (long)DIMN * DIMN;
  if (i4 >= 3 * per) return;
  const float* src = (i4 < per) ? (Wq + i4) : (i4 < 2 * per) ? (Wk + i4 - per) : (Wv + i4 - 2 * per);
  float4 v = *reinterpret_cast<const float4*>(src);
  union {
    bf16 b[4];
    short4 s4;
  } o;
  o.b[0] = __float2bfloat16(v.x);
  o.b[1] = __float2bfloat16(v.y);
  o.b[2] = __float2bfloat16(v.z);
  o.b[3] = __float2bfloat16(v.w);
  *reinterpret_cast<short4*>(w_bf + i4) = o.s4;
}

__global__ void k_prep_wo(const float* __restrict__ Wo, bf16* __restrict__ w_bf) {
  long i4 = ((long)blockIdx.x * blockDim.x + threadIdx.x) * 4;
  if (i4 >= (long)DIMN * DIMN) return;
  float4 v = *reinterpret_cast<const float4*>(Wo + i4);
  union {
    bf16 b[4];
    short4 s4;
  } o;
  o.b[0] = __float2bfloat16(v.x);
  o.b[1] = __float2bfloat16(v.y);
  o.b[2] = __float2bfloat16(v.z);
  o.b[3] = __float2bfloat16(v.w);
  *reinterpret_cast<short4*>(w_bf + i4) = o.s4;
}

// ---------------- GEMM (m97 structure): 128x128 tile, BK=32, dbuf, global_load_lds ----
template <int MODE>
__global__ __launch_bounds__(256) void k_gemm128(const bf16* __restrict__ A,
                                                 const bf16* __restrict__ B,
                                                 float* __restrict__ C, int N, int K,
                                                 const float* __restrict__ bias) {
  __shared__ __align__(16) char smem[32768];
  const int tid = threadIdx.x;
  const int w = tid >> 6, lane = tid & 63;
  const int clo = lane & 15, lhi = lane >> 4;
  const int wr = w >> 1, wc = w & 1;
  const int m0 = blockIdx.y * 128, n0 = blockIdx.x * 128;

  const int srow = tid >> 2, schunk = tid & 3;
  const long agoff0 = (long)(m0 + srow) * K + schunk * 8;
  const long agoff1 = agoff0 + (long)64 * K;
  const long bgoff0 = (long)(n0 + srow) * K + schunk * 8;
  const long bgoff1 = bgoff0 + (long)64 * K;
  const int ldsb = w * 1024;

  f32x4 acc[4][4] = {};

  auto stage = [&](int b, int kb) {
    char* Abuf = &smem[b * 16384];
    char* Bbuf = &smem[b * 16384 + 8192];
    GLOAD_LDS16(A + agoff0 + kb, Abuf + ldsb);
    GLOAD_LDS16(A + agoff1 + kb, Abuf + 4096 + ldsb);
    GLOAD_LDS16(B + bgoff0 + kb, Bbuf + ldsb);
    GLOAD_LDS16(B + bgoff1 + kb, Bbuf + 4096 + ldsb);
  };

  stage(0, 0);
  __syncthreads();
  const int NKS = K / 32;
  int cur = 0;
  for (int ks = 0; ks < NKS; ++ks) {
    if (ks + 1 < NKS) stage(cur ^ 1, (ks + 1) * 32);
    const char* Abuf = &smem[cur * 16384];
    const char* Bbuf = &smem[cur * 16384 + 8192];
    s16x8 af[4], bfr[4];
#pragma unroll
    for (int m = 0; m < 4; ++m)
      af[m] = *reinterpret_cast<const s16x8*>(Abuf + (wr * 64 + m * 16 + clo) * 64 + lhi * 16);
#pragma unroll
    for (int n = 0; n < 4; ++n)
      bfr[n] = *reinterpret_cast<const s16x8*>(Bbuf + (wc * 64 + n * 16 + clo) * 64 + lhi * 16);
#pragma unroll
    for (int m = 0; m < 4; ++m)
#pragma unroll
      for (int n = 0; n < 4; ++n)
        acc[m][n] = __builtin_amdgcn_mfma_f32_16x16x32_bf16(af[m], bfr[n], acc[m][n], 0, 0, 0);
    __syncthreads();
    cur ^= 1;
  }
#pragma unroll
  for (int n = 0; n < 4; ++n) {
    const int col = n0 + wc * 64 + n * 16 + clo;
    const float bv = (MODE == 1) ? bias[col] : 0.f;
#pragma unroll
    for (int m = 0; m < 4; ++m) {
#pragma unroll
      for (int r = 0; r < 4; ++r) {
        const int row = m0 + wr * 64 + m * 16 + lhi * 4 + r;
        if (MODE == 0) {
          C[(long)row * N + col] = acc[m][n][r];
        } else if (row < S_TOT) {
          const int dst = (row >= TTXT) ? (row - TTXT) : (row + (S_TOT - TTXT));
          C[(long)dst * N + col] = acc[m][n][r] + bv;
        }
      }
    }
  }
}

// ---------------- LN + bias + RoPE + repack ----------------
__global__ __launch_bounds__(256) void k_ln_rope_pack(
    const float* __restrict__ qkv, const float* __restrict__ bq, const float* __restrict__ bk,
    const float* __restrict__ bv, const float* __restrict__ lqw, const float* __restrict__ lqb,
    const float* __restrict__ lkw, const float* __restrict__ lkb, const float* __restrict__ cosT,
    const float* __restrict__ sinT, bf16* __restrict__ qb, bf16* __restrict__ kbf,
    bf16* __restrict__ vt) {
  const int sh = blockIdx.x * 4 + (threadIdx.x >> 6);
  const int s = sh / NH, h = sh % NH;
  const int d = threadIdx.x & 63;
  const long qk_idx = ((long)h * S_PAD + s) * HD + d;
  const long vt_idx = ((long)h * HD + d) * S_PAD + s;
  if (s >= S_TOT) {
    qb[qk_idx] = __float2bfloat16(0.f);
    kbf[qk_idx] = __float2bfloat16(0.f);
    vt[vt_idx] = __float2bfloat16(0.f);
    return;
  }
  const long base = (long)s * NQKV + h * HD + d;
  float qv = qkv[base] + bq[h * HD + d];
  float kv = qkv[base + DIMN] + bk[h * HD + d];
  float vv = qkv[base + 2 * DIMN] + bv[h * HD + d];

  auto ln64 = [&](float x, float w, float b2) {
    float sum = x, sq = x * x;
#pragma unroll
    for (int m = 32; m >= 1; m >>= 1) {
      sum += __shfl_xor(sum, m);
      sq += __shfl_xor(sq, m);
    }
    float mu = sum * (1.f / 64.f);
    float var = sq * (1.f / 64.f) - mu * mu;
    return (x - mu) * rsqrtf(var + 1e-5f) * w + b2;
  };
  float qn = ln64(qv, lqw[d], lqb[d]);
  float kn = ln64(kv, lkw[d], lkb[d]);
  if (s >= TTXT) {
    const long ri = (long)(s - TTXT) * HD + d;
    float c = cosT[ri], sn = sinT[ri];
    float qp = __shfl_xor(qn, 1);
    float kp = __shfl_xor(kn, 1);
    float sgn = (d & 1) ? 1.f : -1.f;
    qn = qn * c + sgn * qp * sn;
    kn = kn * c + sgn * kp * sn;
  }
  qb[qk_idx] = __float2bfloat16(qn * 0.1803368801f);  // 0.125 * log2(e)
  kbf[qk_idx] = __float2bfloat16(kn);
  vt[vt_idx] = __float2bfloat16(vv);
}

// ---- flash v4: KV-split x2, swapped 32x32 QK^T, tree reductions, permlane exchanges ----
// Writes PARTIAL (un-normalized O, m, l) per (ks, h, q-row); k_combine merges.
__global__ __launch_bounds__(256) void k_flash4(const bf16* __restrict__ qb,
                                                const bf16* __restrict__ kbf,
                                                const bf16* __restrict__ vt,
                                                float* __restrict__ po,
                                                float* __restrict__ pm,
                                                float* __restrict__ pl) {
  __shared__ __align__(16) char smem[32768];  // dbuf: K 8KB + VT 8KB per buffer
  const int h = blockIdx.x, qt = blockIdx.y, ks = blockIdx.z;
  const int tid = threadIdx.x, w = tid >> 6, lane = tid & 63;
  const int l31 = lane & 31, hf = lane >> 5;
  const bf16* Qh = qb + (long)h * S_PAD * HD;
  const bf16* Kh = kbf + (long)h * S_PAD * HD;
  const bf16* Vh = vt + (long)h * HD * S_PAD;
  const int q0w = qt * 128 + w * 32;
  const int T0 = ks * 18;  // first key-tile of this half

  s16x8 qf[4];
#pragma unroll
  for (int t = 0; t < 4; ++t)
    qf[t] = *reinterpret_cast<const s16x8*>(Qh + (long)(q0w + l31) * HD + t * 16 + hf * 8);

  f32x16 accO[2] = {};
  float m_run = -1e30f;
  float l_run = 0.f;

  const int su = w * 64 + lane;
  const int sr = su >> 3, sc8 = su & 7;
  const long kg0 = (long)sr * HD + ((sc8 ^ (sr & 7)) * 8);
  const long kg1 = kg0 + (long)32 * HD;
  const long vg0 = (long)sr * S_PAD + ((sc8 ^ (sr & 7)) * 8);
  const long vg1 = vg0 + (long)32 * S_PAD;
  const int ldsb = w * 1024;

  auto stage = [&](int b, int kb0) {
    char* Kb = &smem[b * 16384];
    char* Vb = &smem[b * 16384 + 8192];
    GLOAD_LDS16(Kh + (long)kb0 * HD + kg0, Kb + ldsb);
    GLOAD_LDS16(Kh + (long)kb0 * HD + kg1, Kb + 4096 + ldsb);
    GLOAD_LDS16(Vh + kb0 + vg0, Vb + ldsb);
    GLOAD_LDS16(Vh + kb0 + vg1, Vb + 4096 + ldsb);
  };

  auto ldsrd = [&](const char* base, int row, int c) {
    return *reinterpret_cast<const s16x8*>(base + row * 128 + ((c ^ (row & 7)) * 16));
  };
  auto pk2 = [&](float a, float b) -> unsigned {
    __hip_bfloat162 t = __float22bfloat162_rn(make_float2(a, b));
    return *reinterpret_cast<unsigned*>(&t);
  };

  stage(0, T0 * 64);
  __syncthreads();
  int cur = 0;
  for (int kt = 0; kt < 18; ++kt) {
    const int kb0 = (T0 + kt) * 64;
    if (kt + 1 < 18) stage(cur ^ 1, kb0 + 64);
    const char* Kb = &smem[cur * 16384];
    const char* Vb = &smem[cur * 16384 + 8192];

    f32x16 s0 = {}, s1 = {};
#pragma unroll
    for (int t = 0; t < 4; ++t) {
      s16x8 k0 = ldsrd(Kb, l31, 2 * t + hf);
      s16x8 k1 = ldsrd(Kb, 32 + l31, 2 * t + hf);
      s0 = __builtin_amdgcn_mfma_f32_32x32x16_bf16(k0, qf[t], s0, 0, 0, 0);
      s1 = __builtin_amdgcn_mfma_f32_32x32x16_bf16(k1, qf[t], s1, 0, 0, 0);
    }
    if (kb0 + 64 > S_TOT) {
#pragma unroll
      for (int j = 0; j < 16; ++j) {
        const int key = kb0 + (j & 3) + 8 * (j >> 2) + 4 * hf;
        if (key >= S_TOT) s0[j] = -1e30f;
        if (key + 32 >= S_TOT) s1[j] = -1e30f;
      }
    }
    // max: pairwise tree (depth 5) + permlane partner fold
    float tm[16];
#pragma unroll
    for (int j = 0; j < 16; ++j) tm[j] = fmaxf(s0[j], s1[j]);
#pragma unroll
    for (int st = 8; st >= 1; st >>= 1)
#pragma unroll
      for (int i = 0; i < st; ++i) tm[i] = fmaxf(tm[i], tm[i + st]);
    {
      auto r = __builtin_amdgcn_permlane32_swap(__float_as_uint(tm[0]), __float_as_uint(tm[0]),
                                                false, false);
      tm[0] = fmaxf(__uint_as_float(r[0]), __uint_as_float(r[1]));
    }
    const float pmax = tm[0];
    // T13 defer-max (log2 domain, THR=8)
    if (!__all(pmax - m_run <= 8.f)) {
      const float mnew = fmaxf(m_run, pmax);
      const float corr = exp2f(m_run - mnew);
      m_run = mnew;
      l_run *= corr;
#pragma unroll
      for (int j = 0; j < 16; ++j) {
        const float cj = __shfl(corr, (lane & 32) | ((j & 3) + 8 * (j >> 2) + 4 * hf));
        accO[0][j] *= cj;
        accO[1][j] *= cj;
      }
    }
    // exp2 + sum tree
    float ts[16];
#pragma unroll
    for (int j = 0; j < 16; ++j) {
      s0[j] = exp2f(s0[j] - m_run);
      s1[j] = exp2f(s1[j] - m_run);
      ts[j] = s0[j] + s1[j];
    }
#pragma unroll
    for (int st = 8; st >= 1; st >>= 1)
#pragma unroll
      for (int i = 0; i < st; ++i) ts[i] += ts[i + st];
    {
      auto r = __builtin_amdgcn_permlane32_swap(__float_as_uint(ts[0]), __float_as_uint(ts[0]),
                                                false, false);
      l_run += __uint_as_float(r[0]) + __uint_as_float(r[1]);
    }
    // pack P -> bf16 words
    unsigned gw0[8], gw1[8];
#pragma unroll
    for (int i = 0; i < 4; ++i) {
      gw0[2 * i] = pk2(s0[4 * i], s0[4 * i + 1]);
      gw0[2 * i + 1] = pk2(s0[4 * i + 2], s0[4 * i + 3]);
      gw1[2 * i] = pk2(s1[4 * i], s1[4 * i + 1]);
      gw1[2 * i + 1] = pk2(s1[4 * i + 2], s1[4 * i + 3]);
    }
    // assemble PV A-frags via permlane32_swap: (u0,u2)=swap(gw[4t],gw[4t+2]), (u1,u3)=swap(...)
    s16x8 pa[4];
#pragma unroll
    for (int b = 0; b < 2; ++b) {
      unsigned* gw = b ? gw1 : gw0;
#pragma unroll
      for (int t = 0; t < 2; ++t) {
        auto rA = __builtin_amdgcn_permlane32_swap(gw[4 * t + 0], gw[4 * t + 2], false, false);
        auto rB = __builtin_amdgcn_permlane32_swap(gw[4 * t + 1], gw[4 * t + 3], false, false);
        union {
          unsigned u[4];
          s16x8 v;
        } A;
        A.u[0] = rA[0];
        A.u[1] = rB[0];
        A.u[2] = rA[1];
        A.u[3] = rB[1];
        pa[b * 2 + t] = A.v;
      }
    }
#pragma unroll
    for (int t4 = 0; t4 < 4; ++t4) {
      s16x8 v0 = ldsrd(Vb, l31, 2 * t4 + hf);
      s16x8 v1 = ldsrd(Vb, 32 + l31, 2 * t4 + hf);
      accO[0] = __builtin_amdgcn_mfma_f32_32x32x16_bf16(pa[t4], v0, accO[0], 0, 0, 0);
      accO[1] = __builtin_amdgcn_mfma_f32_32x32x16_bf16(pa[t4], v1, accO[1], 0, 0, 0);
    }
    __syncthreads();
    cur ^= 1;
  }
  // epilogue: write partials (no division)
  const long rowbase = ((long)(ks * NH + h)) * S_PAD + q0w;
  if (hf == 0) {
    pm[rowbase + l31] = m_run;
    pl[rowbase + l31] = l_run;
  }
#pragma unroll
  for (int j = 0; j < 16; ++j) {
    const int pat = (j & 3) + 8 * (j >> 2) + 4 * hf;
    float* dst = po + (rowbase + pat) * HD + l31;
    dst[0] = accO[0][j];
    dst[32] = accO[1][j];
  }
}

// ---------------- combine the two KV-halves ----------------
__global__ __launch_bounds__(256) void k_combine(const float* __restrict__ po,
                                                 const float* __restrict__ pm,
                                                 const float* __restrict__ pl,
                                                 bf16* __restrict__ ao) {
  const int idx = blockIdx.x * 256 + threadIdx.x;
  const int d = idx & 63;
  const int row = (idx >> 6) % S_PAD;
  const int h = idx / (S_PAD * 64);
  if (row >= S_TOT) return;
  const long r1 = (long)h * S_PAD + row;
  const long r2 = (long)(NH + h) * S_PAD + row;
  const float m1 = pm[r1], m2 = pm[r2];
  const float m = fmaxf(m1, m2);
  const float a1 = exp2f(m1 - m), a2 = exp2f(m2 - m);
  const float o = po[r1 * HD + d] * a1 + po[r2 * HD + d] * a2;
  const float l = pl[r1] * a1 + pl[r2] * a2;
  ao[(long)row * DIMN + h * HD + d] = __float2bfloat16(o / l);
}

extern "C" void kernel_launch(void* const* d_in, const int* in_sizes, int n_in, void* d_out,
                              int out_size, void* d_ws, size_t ws_size, hipStream_t stream) {
  const float* hid = (const float*)d_in[0];
  const float* enc = (const float*)d_in[1];
  const float* rc = (const float*)d_in[2];
  const float* rs = (const float*)d_in[3];
  const float* Wq = (const float*)d_in[4];
  const float* bq = (const float*)d_in[5];
  const float* Wk = (const float*)d_in[6];
  const float* bk = (const float*)d_in[7];
  const float* Wv = (const float*)d_in[8];
  const float* bv = (const float*)d_in[9];
  const float* lqw = (const float*)d_in[10];
  const float* lqb = (const float*)d_in[11];
  const float* lkw = (const float*)d_in[12];
  const float* lkb = (const float*)d_in[13];
  const float* Wo = (const float*)d_in[14];
  const float* bo = (const float*)d_in[15];
  float* out = (float*)d_out;

  char* ws = (char*)d_ws;
  size_t off = 0;
  float* qkv_raw = (float*)(ws + off);
  off += (size_t)S_PAD * NQKV * 4;  // 53.1 MB; reused by flash partials after pack
  bf16* h_bf = (bf16*)(ws + off);
  off += (size_t)S_PAD * DIMN * 2;
  bf16* wqkv = (bf16*)(ws + off);
  off += (size_t)3 * DIMN * DIMN * 2;
  bf16* wo = (bf16*)(ws + off);
  off += (size_t)DIMN * DIMN * 2;
  bf16* q_bf = (bf16*)(ws + off);
  off += (size_t)NH * S_PAD * HD * 2;
  bf16* k_bf = (bf16*)(ws + off);
  off += (size_t)NH * S_PAD * HD * 2;
  bf16* vt_bf = (bf16*)(ws + off);
  off += (size_t)NH * HD * S_PAD * 2;
  bf16* at_bf = (bf16*)(ws + off);
  off += (size_t)S_PAD * DIMN * 2;

  // flash partials alias qkv_raw (dead after k_ln_rope_pack; rewritten every call)
  char* pw = (char*)qkv_raw;
  float* po = (float*)pw;                                       // 2*NH*S_PAD*HD*4 = 35.4 MB
  float* pm = (float*)(pw + (size_t)2 * NH * S_PAD * HD * 4);   // 0.55 MB
  float* pl = pm + (size_t)2 * NH * S_PAD;                      // 0.55 MB (total 36.5 < 53.1)

  k_prep_h<<<((S_PAD * DIMN) / 4 + 255) / 256, 256, 0, stream>>>(hid, enc, h_bf);
  k_prep_wqkv<<<((3 * DIMN * DIMN) / 4 + 255) / 256, 256, 0, stream>>>(Wq, Wk, Wv, wqkv);
  k_prep_wo<<<((DIMN * DIMN) / 4 + 255) / 256, 256, 0, stream>>>(Wo, wo);
  k_gemm128<0><<<dim3(NQKV / 128, S_PAD / 128), 256, 0, stream>>>(h_bf, wqkv, qkv_raw, NQKV,
                                                                  DIMN, nullptr);
  k_ln_rope_pack<<<S_PAD * NH / 4, 256, 0, stream>>>(qkv_raw, bq, bk, bv, lqw, lqb, lkw, lkb, rc,
                                                     rs, q_bf, k_bf, vt_bf);
  k_flash4<<<dim3(NH, S_PAD / 128, 2), 256, 0, stream>>>(q_bf, k_bf, vt_bf, po, pm, pl);
  k_combine<<<NH * S_PAD * HD / 256, 256, 0, stream>>>(po, pm, pl, at_bf);
  k_gemm128<1><<<dim3(DIMN / 128, S_PAD / 128), 256, 0, stream>>>(at_bf, wo, out, DIMN, DIMN, bo);
}